// Round 2
// baseline (4864.455 us; speedup 1.0000x reference)
//
#include <hip/hip_runtime.h>
#include <math.h>

#define HH 192
#define WW 192
#define HWQ 36864          // 192*192
#define NB 2
#define NT 3
#define CDIM 96

// ---------- helpers ----------
__device__ __forceinline__ float lrelu02(float v){ return v > 0.f ? v : 0.2f*v; }

__device__ __forceinline__ void make_taps(int y, int x, int* off, float* mm){
    #pragma unroll
    for (int k=0;k<9;++k){
        int dy = k/3 - 1, dx = k - (k/3)*3 - 1;
        int yy = y+dy, xx = x+dx;
        bool ok = (yy>=0) && (yy<HH) && (xx>=0) && (xx<WW);
        int yc = yy < 0 ? 0 : (yy > HH-1 ? HH-1 : yy);
        int xc = xx < 0 ? 0 : (xx > WW-1 ? WW-1 : xx);
        off[k] = yc*WW + xc;
        mm[k]  = ok ? 1.f : 0.f;
    }
}

// ---------- RDB ----------
// copy F frame channels into cat buffer (layout: [6 frames][224 ch][HW])
__global__ void k_copy_cat(const float* __restrict__ F, float* __restrict__ cat){
    int p  = blockIdx.x*256 + threadIdx.x;
    int c  = blockIdx.y;
    int fi = blockIdx.z;
    int b = fi/NT, t = fi - b*NT;
    cat[((size_t)fi*224 + c)*HWQ + p] = F[(((size_t)b*CDIM + c)*NT + t)*HWQ + p];
}

// dense 3x3 conv: reads cat[0:Cin], writes leaky output at cat[coff:coff+32]
__global__ void k_dense3x3(float* __restrict__ cat, const float* __restrict__ w,
                           int Cin, int coff){
    int p = blockIdx.x*256 + threadIdx.x;
    int y = p/WW, x = p - y*WW;
    int og = blockIdx.y;          // 4 groups of 8 couts
    int fi = blockIdx.z;
    const float* in = cat + (size_t)fi*224*HWQ;
    int off[9]; float mm[9];
    make_taps(y,x,off,mm);
    float acc[8];
    #pragma unroll
    for (int j=0;j<8;++j) acc[j]=0.f;
    const float* wbase = w + (size_t)og*8*Cin*9;
    for (int ci=0; ci<Cin; ++ci){
        const float* s  = in + (size_t)ci*HWQ;
        const float* wp = wbase + (size_t)ci*9;
        #pragma unroll
        for (int k=0;k<9;++k){
            float v = s[off[k]] * mm[k];
            #pragma unroll
            for (int j=0;j<8;++j)
                acc[j] = fmaf(v, wp[(size_t)j*Cin*9 + k], acc[j]);
        }
    }
    float* o = cat + (size_t)fi*224*HWQ + (size_t)(coff + og*8)*HWQ + p;
    #pragma unroll
    for (int j=0;j<8;++j) o[(size_t)j*HWQ] = lrelu02(acc[j]);
}

// final RDB 1x1 (224->96) + bias + residual, strided output into Fo (B,96,T,H,W)
__global__ void k_rdb_final(const float* __restrict__ cat, const float* __restrict__ w,
                            const float* __restrict__ bias, const float* __restrict__ F,
                            float* __restrict__ Fo){
    int p = blockIdx.x*256 + threadIdx.x;
    int og = blockIdx.y;          // 3 groups of 32
    int fi = blockIdx.z;
    int b = fi/NT, t = fi - b*NT;
    const float* in = cat + (size_t)fi*224*HWQ + p;
    float acc[32];
    #pragma unroll
    for (int j=0;j<32;++j) acc[j]=0.f;
    const float* wbase = w + (size_t)og*32*224;
    for (int ci=0; ci<224; ++ci){
        float v = in[(size_t)ci*HWQ];
        #pragma unroll
        for (int j=0;j<32;++j)
            acc[j] = fmaf(v, wbase[(size_t)j*224 + ci], acc[j]);
    }
    #pragma unroll
    for (int j=0;j<32;++j){
        int c = og*32 + j;
        size_t idx = (((size_t)b*CDIM + c)*NT + t)*HWQ + p;
        Fo[idx] = acc[j] + bias[c] + F[idx];
    }
}

// ---------- flow convs ----------
// cf1: z = concat(F0_rep, Fo) (192 ch) -> 24, 3x3, leaky. t1 layout [frame][24][HW]
__global__ void k_cf1(const float* __restrict__ F0c, const float* __restrict__ Fo,
                      const float* __restrict__ w, float* __restrict__ t1){
    int p = blockIdx.x*256 + threadIdx.x;
    int y = p/WW, x = p - y*WW;
    int og = blockIdx.y;          // 3 groups of 8
    int fi = blockIdx.z;
    int b = fi/NT, t = fi - b*NT;
    int off[9]; float mm[9];
    make_taps(y,x,off,mm);
    float acc[8];
    #pragma unroll
    for (int j=0;j<8;++j) acc[j]=0.f;
    const float* wbase = w + (size_t)og*8*192*9;
    for (int ci=0; ci<192; ++ci){
        const float* s = (ci < 96)
            ? F0c + ((size_t)b*CDIM + ci)*HWQ
            : Fo  + (((size_t)b*CDIM + (ci-96))*NT + t)*HWQ;
        const float* wp = wbase + (size_t)ci*9;
        #pragma unroll
        for (int k=0;k<9;++k){
            float v = s[off[k]] * mm[k];
            #pragma unroll
            for (int j=0;j<8;++j)
                acc[j] = fmaf(v, wp[(size_t)j*192*9 + k], acc[j]);
        }
    }
    float* o = t1 + ((size_t)fi*24 + og*8)*HWQ + p;
    #pragma unroll
    for (int j=0;j<8;++j) o[(size_t)j*HWQ] = lrelu02(acc[j]);
}

// cf2: 24->24 3x3, no act, output to f (B,24,T,H,W)
__global__ void k_cf2(const float* __restrict__ t1, const float* __restrict__ w,
                      float* __restrict__ fout){
    int p = blockIdx.x*256 + threadIdx.x;
    int y = p/WW, x = p - y*WW;
    int og = blockIdx.y;          // 3 groups of 8
    int fi = blockIdx.z;
    int b = fi/NT, t = fi - b*NT;
    int off[9]; float mm[9];
    make_taps(y,x,off,mm);
    float acc[8];
    #pragma unroll
    for (int j=0;j<8;++j) acc[j]=0.f;
    const float* in = t1 + (size_t)fi*24*HWQ;
    const float* wbase = w + (size_t)og*8*24*9;
    for (int ci=0; ci<24; ++ci){
        const float* s  = in + (size_t)ci*HWQ;
        const float* wp = wbase + (size_t)ci*9;
        #pragma unroll
        for (int k=0;k<9;++k){
            float v = s[off[k]] * mm[k];
            #pragma unroll
            for (int j=0;j<8;++j)
                acc[j] = fmaf(v, wp[(size_t)j*24*9 + k], acc[j]);
        }
    }
    #pragma unroll
    for (int j=0;j<8;++j){
        int c = og*8 + j;
        fout[(((size_t)b*24 + c)*NT + t)*HWQ + p] = acc[j];
    }
}

// ---------- multiflow backwarp ----------
__global__ void k_bwarp(const float* __restrict__ Fo, const float* __restrict__ fflow,
                        float* __restrict__ warped){
    int p = blockIdx.x*256 + threadIdx.x;
    int y = p/WW, x = p - y*WW;
    int nf = blockIdx.y;          // 0..7
    int fi = blockIdx.z;
    int b = fi/NT, t = fi - b*NT;
    size_t fb = (((size_t)b*24 + nf*3)*NT + t)*HWQ + p;
    float fx = fflow[fb];
    float fy = fflow[fb + (size_t)NT*HWQ];
    float fwv= fflow[fb + (size_t)2*NT*HWQ];
    float wgt = 1.f/(1.f + expf(-fwv));
    float fxp = (float)x + fx;       // (gx+1)*(W-1)/2 == x + flow_x
    float fyp = (float)y + fy;
    float x0f = floorf(fxp), y0f = floorf(fyp);
    int x0 = (int)x0f, y0 = (int)y0f;
    int x1 = x0+1,    y1 = y0+1;
    float wx1 = fxp - x0f, wy1 = fyp - y0f;
    float wx0 = 1.f - wx1, wy0 = 1.f - wy1;
    bool okx0 = (x0>=0)&&(x0<WW), okx1 = (x1>=0)&&(x1<WW);
    bool oky0 = (y0>=0)&&(y0<HH), oky1 = (y1>=0)&&(y1<HH);
    int xc0 = x0<0?0:(x0>WW-1?WW-1:x0);
    int xc1 = x1<0?0:(x1>WW-1?WW-1:x1);
    int yc0 = y0<0?0:(y0>HH-1?HH-1:y0);
    int yc1 = y1<0?0:(y1>HH-1?HH-1:y1);
    float w00 = wx0*wy0 * ((okx0&&oky0)?1.f:0.f);
    float w10 = wx1*wy0 * ((okx1&&oky0)?1.f:0.f);
    float w01 = wx0*wy1 * ((okx0&&oky1)?1.f:0.f);
    float w11 = wx1*wy1 * ((okx1&&oky1)?1.f:0.f);
    int o00 = yc0*WW+xc0, o10 = yc0*WW+xc1, o01 = yc1*WW+xc0, o11 = yc1*WW+xc1;
    #pragma unroll
    for (int c=0;c<12;++c){
        size_t ch = (size_t)b*CDIM + nf*12 + c;
        const float* src = Fo + (ch*NT + t)*HWQ;
        float v = w00*src[o00] + w10*src[o10] + w01*src[o01] + w11*src[o11];
        warped[(ch*NT + t)*HWQ + p] = v * wgt;
    }
}

// ---------- generic 1x1 conv, Cout = gridDim.y*32, optional accumulate ----------
__global__ void k_conv1x1(const float* __restrict__ in, const float* __restrict__ w,
                          float* __restrict__ out, int Cin, int accflag){
    int p = blockIdx.x*256 + threadIdx.x;
    int og = blockIdx.y;
    int b  = blockIdx.z;
    int Cout = gridDim.y*32;
    const float* ip = in + (size_t)b*Cin*HWQ + p;
    float acc[32];
    #pragma unroll
    for (int j=0;j<32;++j) acc[j]=0.f;
    const float* wbase = w + (size_t)og*32*Cin;
    for (int ci=0; ci<Cin; ++ci){
        float v = ip[(size_t)ci*HWQ];
        #pragma unroll
        for (int j=0;j<32;++j)
            acc[j] = fmaf(v, wbase[(size_t)j*Cin + ci], acc[j]);
    }
    float* op = out + ((size_t)b*Cout + og*32)*HWQ + p;
    #pragma unroll
    for (int j=0;j<32;++j){
        float r = acc[j];
        if (accflag) r += op[(size_t)j*HWQ];
        op[(size_t)j*HWQ] = r;
    }
}

// ---------- layernorm over 96 channels (+optional F0 add) ----------
__global__ void k_ln(const float* __restrict__ xin, const float* __restrict__ wln,
                     const float* __restrict__ bln, const float* __restrict__ f0,
                     float* __restrict__ outp){
    int p = blockIdx.x*256 + threadIdx.x;
    int b = blockIdx.z;
    const float* ip = xin + (size_t)b*CDIM*HWQ + p;
    float s=0.f, ss=0.f;
    for (int c=0;c<CDIM;++c){ float v=ip[(size_t)c*HWQ]; s+=v; ss=fmaf(v,v,ss); }
    float mu  = s*(1.f/96.f);
    float var = ss*(1.f/96.f) - mu*mu;
    float rstd = rsqrtf(var + 1e-5f);
    float* op = outp + (size_t)b*CDIM*HWQ + p;
    const float* fp = f0 ? (f0 + (size_t)b*CDIM*HWQ + p) : (const float*)0;
    for (int c=0;c<CDIM;++c){
        float v = (ip[(size_t)c*HWQ]-mu)*rstd*wln[c] + bln[c];
        if (fp) v += fp[(size_t)c*HWQ];
        op[(size_t)c*HWQ] = v;
    }
}

// ---------- depthwise 3x3 ----------
__global__ void k_dw3x3(const float* __restrict__ in, const float* __restrict__ w,
                        float* __restrict__ outp, int C){
    int p = blockIdx.x*256 + threadIdx.x;
    int y = p/WW, x = p - y*WW;
    int c = blockIdx.y, b = blockIdx.z;
    int off[9]; float mm[9];
    make_taps(y,x,off,mm);
    const float* s  = in + ((size_t)b*C + c)*HWQ;
    const float* wp = w + (size_t)c*9;
    float a=0.f;
    #pragma unroll
    for (int k=0;k<9;++k) a = fmaf(s[off[k]]*mm[k], wp[k], a);
    outp[((size_t)b*C + c)*HWQ + p] = a;
}

// ---------- q/k L2-norm scales:  scales[which*192 + b*96 + c] = 1/max(||row||,eps) ----------
__global__ void k_qknorm(const float* __restrict__ qkv2, float* __restrict__ scales){
    int r = blockIdx.x;                 // 0..383
    int which = r/192, rem = r - which*192, b = rem/96, c = rem - b*96;
    const float* s = qkv2 + ((size_t)b*288 + which*96 + c)*HWQ;
    float ss = 0.f;
    for (int n=threadIdx.x; n<HWQ; n+=256){ float v=s[n]; ss = fmaf(v,v,ss); }
    #pragma unroll
    for (int o=32;o>0;o>>=1) ss += __shfl_down(ss, o, 64);
    __shared__ float sm[4];
    if ((threadIdx.x&63)==0) sm[threadIdx.x>>6]=ss;
    __syncthreads();
    if (threadIdx.x==0){
        float tot = sm[0]+sm[1]+sm[2]+sm[3];
        scales[r] = 1.f / fmaxf(sqrtf(tot), 1e-12f);
    }
}

// ---------- S = (q_n . k_n^T)*temp ----------
__global__ void k_attnS(const float* __restrict__ qkv2, const float* __restrict__ scales,
                        const float* __restrict__ tempp, float* __restrict__ S){
    int id = blockIdx.x;                // 0..191 : (b, head, i)
    int b = id/96, rem = id - b*96, head = rem/12, i = rem - head*12;
    const float* q  = qkv2 + ((size_t)b*288 + head*12 + i)*HWQ;
    const float* kb = qkv2 + ((size_t)b*288 + 96 + head*12)*HWQ;
    float acc[12];
    #pragma unroll
    for (int j=0;j<12;++j) acc[j]=0.f;
    for (int n=threadIdx.x; n<HWQ; n+=256){
        float qv = q[n];
        #pragma unroll
        for (int j=0;j<12;++j) acc[j] = fmaf(qv, kb[(size_t)j*HWQ + n], acc[j]);
    }
    __shared__ float sm[48];
    int lane = threadIdx.x & 63, wid = threadIdx.x >> 6;
    #pragma unroll
    for (int j=0;j<12;++j){
        float v = acc[j];
        #pragma unroll
        for (int o=32;o>0;o>>=1) v += __shfl_down(v, o, 64);
        if (lane==0) sm[wid*12 + j] = v;
    }
    __syncthreads();
    if (threadIdx.x < 12){
        int j = threadIdx.x;
        float tot = sm[j] + sm[12+j] + sm[24+j] + sm[36+j];
        float val = tot * scales[b*96 + head*12 + i]
                        * scales[192 + b*96 + head*12 + j]
                        * tempp[head];
        S[((size_t)(b*8+head)*12 + i)*12 + j] = val;
    }
}

__global__ void k_softmax12(float* __restrict__ S){
    int r = threadIdx.x;
    if (r < 192){
        float* row = S + (size_t)r*12;
        float mx = row[0];
        #pragma unroll
        for (int j=1;j<12;++j) mx = fmaxf(mx, row[j]);
        float e[12]; float sum=0.f;
        #pragma unroll
        for (int j=0;j<12;++j){ e[j]=expf(row[j]-mx); sum+=e[j]; }
        float inv = 1.f/sum;
        #pragma unroll
        for (int j=0;j<12;++j) row[j] = e[j]*inv;
    }
}

// ---------- out = attn @ v ----------
__global__ void k_attnV(const float* __restrict__ qkv2, const float* __restrict__ S,
                        float* __restrict__ av){
    __shared__ float P[1152];           // 8 heads * 12 * 12
    int b = blockIdx.z;
    for (int idx=threadIdx.x; idx<1152; idx+=256) P[idx] = S[(size_t)b*1152 + idx];
    __syncthreads();
    int p = blockIdx.x*256 + threadIdx.x;
    #pragma unroll
    for (int head=0; head<8; ++head){
        float vv[12];
        const float* vb = qkv2 + ((size_t)b*288 + 192 + head*12)*HWQ + p;
        #pragma unroll
        for (int j=0;j<12;++j) vv[j] = vb[(size_t)j*HWQ];
        #pragma unroll
        for (int i=0;i<12;++i){
            const float* Pr = &P[(head*12 + i)*12];
            float s = 0.f;
            #pragma unroll
            for (int j=0;j<12;++j) s = fmaf(Pr[j], vv[j], s);
            av[((size_t)b*CDIM + head*12 + i)*HWQ + p] = s;
        }
    }
}

// ---------- fused FFN depthwise + GEGLU gate ----------
__global__ void k_dwgate(const float* __restrict__ y_, const float* __restrict__ w,
                         float* __restrict__ g){
    int p = blockIdx.x*256 + threadIdx.x;
    int yy = p/WW, x = p - yy*WW;
    int c = blockIdx.y;                 // 0..191
    int b = blockIdx.z;
    int off[9]; float mm[9];
    make_taps(yy,x,off,mm);
    const float* s1 = y_ + ((size_t)b*384 + c)*HWQ;
    const float* s2 = y_ + ((size_t)b*384 + 192 + c)*HWQ;
    const float* w1 = w + (size_t)c*9;
    const float* w2 = w + (size_t)(192 + c)*9;
    float a1=0.f, a2=0.f;
    #pragma unroll
    for (int k=0;k<9;++k){
        float v1 = s1[off[k]]*mm[k]; a1 = fmaf(v1, w1[k], a1);
        float v2 = s2[off[k]]*mm[k]; a2 = fmaf(v2, w2[k], a2);
    }
    float ge = 0.5f*a1*(1.f + erff(a1*0.70710678118654752f));
    g[((size_t)b*192 + c)*HWQ + p] = ge*a2;
}

// ---------- host ----------
extern "C" void kernel_launch(void* const* d_in, const int* in_sizes, int n_in,
                              void* d_out, int out_size, void* d_ws, size_t ws_size,
                              hipStream_t stream){
    const float* F     = (const float*)d_in[0];
    const float* F0c   = (const float*)d_in[1];
    const float* dw0   = (const float*)d_in[2];
    const float* dw1   = (const float*)d_in[3];
    const float* dw2   = (const float*)d_in[4];
    const float* dw3   = (const float*)d_in[5];
    const float* rdbw  = (const float*)d_in[6];
    const float* rdbb  = (const float*)d_in[7];
    const float* cf1w  = (const float*)d_in[8];
    const float* cf2w  = (const float*)d_in[9];
    const float* cFww  = (const float*)d_in[10];
    const float* n1w   = (const float*)d_in[11];
    const float* n1b   = (const float*)d_in[12];
    const float* temp  = (const float*)d_in[13];
    const float* qkvw  = (const float*)d_in[14];
    const float* qkvdw = (const float*)d_in[15];
    const float* projw = (const float*)d_in[16];
    const float* n2w   = (const float*)d_in[17];
    const float* n2b   = (const float*)d_in[18];
    const float* pinw  = (const float*)d_in[19];
    const float* ffndw = (const float*)d_in[20];
    const float* poutw = (const float*)d_in[21];

    float* out = (float*)d_out;
    float* Fo  = out;                    // 2*96*3*HW = 21233664
    float* Fw  = out + 21233664;         // 2*96*HW   =  7077888
    float* fb  = out + 28311552;         // 2*24*3*HW =  5308416

    // workspace arena (floats), with overlays:
    float* ws     = (float*)d_ws;
    float* cat    = ws;                  // [0, 49545216)  RDB cat (6*224*HW), dead after RDB
    float* t1     = ws;                  // [0, 5308416)   cf1 out, dead after cf2
    float* warped = ws;                  // [0, 21233664)  dead after convFw
    float* qkvA   = ws;                  // [0, 21233664)  attention qkv (pre-dw)
    float* qkv2B  = ws + 21233664;       // [21233664, 42467328) qkv after dw
    float* ybuf   = ws;                  // [0, 28311552)  FFN hidden (overlays dead qkv)
    float* gated  = ws + 28311552;       // [28311552, 42467328)
    float* xin    = ws + 42467328;       // [42467328, 49545216)
    float* av     = ws + 49545216;       // [49545216, 56623104)
    float* scales = ws + 56623104;       // 384 f
    float* Sbuf   = ws + 56623488;       // 2304 f

    dim3 blk(256,1,1);

    // RDB
    k_copy_cat <<<dim3(144,96,6),blk,0,stream>>>(F, cat);
    k_dense3x3 <<<dim3(144,4,6),blk,0,stream>>>(cat, dw0,  96,  96);
    k_dense3x3 <<<dim3(144,4,6),blk,0,stream>>>(cat, dw1, 128, 128);
    k_dense3x3 <<<dim3(144,4,6),blk,0,stream>>>(cat, dw2, 160, 160);
    k_dense3x3 <<<dim3(144,4,6),blk,0,stream>>>(cat, dw3, 192, 192);
    k_rdb_final<<<dim3(144,3,6),blk,0,stream>>>(cat, rdbw, rdbb, F, Fo);

    // flow
    k_cf1<<<dim3(144,3,6),blk,0,stream>>>(F0c, Fo, cf1w, t1);
    k_cf2<<<dim3(144,3,6),blk,0,stream>>>(t1, cf2w, fb);

    // warp + fuse
    k_bwarp  <<<dim3(144,8,6),blk,0,stream>>>(Fo, fb, warped);
    k_conv1x1<<<dim3(144,3,2),blk,0,stream>>>(warped, cFww, Fw, 288, 0);

    // 2x MAB
    for (int i=0;i<2;++i){
        k_ln     <<<dim3(144,1,2),blk,0,stream>>>(Fw, n1w+i*96, n1b+i*96, F0c, xin);
        k_conv1x1<<<dim3(144,9,2),blk,0,stream>>>(xin, qkvw + (size_t)i*288*96, qkvA, 96, 0);
        k_dw3x3  <<<dim3(144,288,2),blk,0,stream>>>(qkvA, qkvdw + (size_t)i*288*9, qkv2B, 288);
        k_qknorm <<<dim3(384,1,1),blk,0,stream>>>(qkv2B, scales);
        k_attnS  <<<dim3(192,1,1),blk,0,stream>>>(qkv2B, scales, temp + i*8, Sbuf);
        k_softmax12<<<dim3(1,1,1),blk,0,stream>>>(Sbuf);
        k_attnV  <<<dim3(144,1,2),blk,0,stream>>>(qkv2B, Sbuf, av);
        k_conv1x1<<<dim3(144,3,2),blk,0,stream>>>(av, projw + (size_t)i*96*96, Fw, 96, 1);

        k_ln     <<<dim3(144,1,2),blk,0,stream>>>(Fw, n2w+i*96, n2b+i*96, (const float*)0, xin);
        k_conv1x1<<<dim3(144,12,2),blk,0,stream>>>(xin, pinw + (size_t)i*384*96, ybuf, 96, 0);
        k_dwgate <<<dim3(144,192,2),blk,0,stream>>>(ybuf, ffndw + (size_t)i*384*9, gated);
        k_conv1x1<<<dim3(144,3,2),blk,0,stream>>>(gated, poutw + (size_t)i*96*192, Fw, 192, 1);
    }
}